// Round 1
// baseline (446.901 us; speedup 1.0000x reference)
//
#include <hip/hip_runtime.h>

#define LDSW 264   // bf16 elems per LDS row (256 + 8 pad -> 528B stride, banks rotate by 4)
#define YST  132   // f32 elems per Y/K1 row (128 + 4 pad)

typedef __attribute__((ext_vector_type(8))) short bf16x8;
typedef __attribute__((ext_vector_type(4))) float f32x4;

__device__ __forceinline__ unsigned short f2bf(float f) {
    unsigned u = __float_as_uint(f);
    u += 0x7fffu + ((u >> 16) & 1u);          // RNE to bf16
    return (unsigned short)(u >> 16);
}
__device__ __forceinline__ float bf2f(unsigned short h) {
    return __uint_as_float(((unsigned)h) << 16);
}

// ---------------- precompute: weights -> MFMA B-fragment layout, hi/lo bf16 planes ----
// F layout: [plane(2)][nt][kc][lane(64)][j(8)] ; value = W[n*(K)+k], n=nt*16+(l&15), k=kc*32+(l>>4)*8+j
template<int KC>
__global__ __launch_bounds__(256) void pk_w(const float* __restrict__ W,
                                            unsigned short* __restrict__ F) {
    int u = blockIdx.x * 256 + threadIdx.x;       // 16*KC*512 total
    int j = u & 7, l = (u >> 3) & 63;
    int kc = (u >> 9) % KC, nt = (u >> 9) / KC;
    int n = nt * 16 + (l & 15);
    int k = kc * 32 + (l >> 4) * 8 + j;
    float w = W[n * (KC * 32) + k];
    unsigned short hi = f2bf(w);
    F[u] = hi;
    F[16 * KC * 512 + u] = f2bf(w - bf2f(hi));
}

// A_r contraction: F[r][plane][nt(8)][kc(8)][lane][j]; B[k=v][n=h] = sum_l Wm[(h*62+l)*256+v]*logsig[r,1+l]
__global__ __launch_bounds__(256) void pk_a3(const float* __restrict__ Wm,
                                             const float* __restrict__ logsig,
                                             unsigned short* __restrict__ F) {
    __shared__ float ls[32][62];
    int t = threadIdx.x;
    for (int e = t; e < 32 * 62; e += 256)
        ls[e / 62][e % 62] = logsig[(e / 62) * 63 + 1 + (e % 62)];
    __syncthreads();
    int u = blockIdx.x * 256 + t;                 // 32768 total
    int j = u & 7, l = (u >> 3) & 63, kc = (u >> 9) & 7, nt = (u >> 12) & 7;
    int h = nt * 16 + (l & 15);
    int v = kc * 32 + (l >> 4) * 8 + j;
    float acc[32];
#pragma unroll
    for (int r = 0; r < 32; r++) acc[r] = 0.f;
    for (int ll = 0; ll < 62; ll++) {
        float wv = Wm[(h * 62 + ll) * 256 + v];
#pragma unroll
        for (int r = 0; r < 32; r++) acc[r] += wv * ls[r][ll];
    }
    for (int r = 0; r < 32; r++) {
        unsigned short hi = f2bf(acc[r]);
        F[r * 65536 + u] = hi;
        F[r * 65536 + 32768 + u] = f2bf(acc[r] - bf2f(hi));
    }
}

__global__ __launch_bounds__(256) void pk_c(const float* __restrict__ bm,
                                            const float* __restrict__ logsig,
                                            float* __restrict__ C) {
    int u = blockIdx.x * 256 + threadIdx.x;       // 4096 = [r(32)][h(128)]
    int r = u >> 7, h = u & 127;
    float acc = 0.f;
    for (int ll = 0; ll < 62; ll++) acc += bm[h * 62 + ll] * logsig[r * 63 + 1 + ll];
    C[u] = acc;
}

// ---------------- main fused kernel: 32 blocks x 16 rows, 4 waves, full 20-step Heun ---
__global__ __launch_bounds__(256) void rde_main(
    const float* __restrict__ ts, const float* __restrict__ x0,
    const float* __restrict__ intervals,
    const float* __restrict__ b1g, const float* __restrict__ b2g,
    const float* __restrict__ Win, const float* __restrict__ bin,
    const float* __restrict__ Wout, const float* __restrict__ bout,
    const unsigned short* __restrict__ W1F, const unsigned short* __restrict__ W2F,
    const unsigned short* __restrict__ A3F, const float* __restrict__ c_all,
    float* __restrict__ out)
{
    __shared__ unsigned short PAhi[16 * LDSW], PAlo[16 * LDSW];   // ping buffer (hi/lo bf16)
    __shared__ unsigned short PBhi[16 * LDSW], PBlo[16 * LDSW];   // pong buffer
    __shared__ float Y[16 * YST], K1[16 * YST];
    __shared__ float ivl[33];
    __shared__ int   r_arr[40];
    __shared__ float s_arr[40];
    __shared__ float lg[16][12];

    const int t    = threadIdx.x;
    const int lane = t & 63;
    const int wv   = t >> 6;        // wave 0..3
    const int m16  = lane & 15;
    const int q    = lane >> 4;
    const int row0 = blockIdx.x * 16;

    if (t < 33) ivl[t] = intervals[t];
    __syncthreads();

    const float ts0 = ts[0];
    const float dt  = __fdiv_rn(ts[32] - ts0, 20.0f);   // bit-exact vs reference

    if (t < 40) {   // precompute searchsorted idx + 1/delta for all 40 VF evals
        int i = t >> 1;
        float tv = ts0 + (float)i * dt;
        if (t & 1) tv += dt;
        int p = 0;
        for (int j2 = 0; j2 < 32; j2++) p += (ivl[1 + j2] < tv) ? 1 : 0;
        int idx = p + 1;
        idx = idx < 1 ? 1 : idx;
        idx = idx > 32 ? 32 : idx;
        r_arr[t] = idx - 1;
        s_arr[t] = __fdiv_rn(1.0f, ivl[idx] - ivl[idx - 1]);
    }

    // y0 = x0 @ Win.T + bin
    for (int e = t; e < 2048; e += 256) {
        int m = e >> 7, h = e & 127;
        float acc = bin[h];
        const float* xr = x0 + (row0 + m) * 5;
#pragma unroll
        for (int d = 0; d < 5; d++) acc += xr[d] * Win[h * 5 + d];
        Y[m * YST + h] = acc;
    }
    __syncthreads();
    // initial bf16 hi/lo split of y -> ping buffer (cols 0..127)
    for (int e = t; e < 2048; e += 256) {
        int m = e >> 7, k = e & 127;
        float v = Y[m * YST + k];
        unsigned short hi = f2bf(v);
        PAhi[m * LDSW + k] = hi;
        PAlo[m * LDSW + k] = f2bf(v - bf2f(hi));
    }
    __syncthreads();

    // stage 1/2: D(16x256) = act( A(16xK) * W(Kx256) + bias ), bf16x3 split product
    auto stage12 = [&](const unsigned short* iH, const unsigned short* iL,
                       unsigned short* oH, unsigned short* oL,
                       const unsigned short* WF, int KC, int planeE,
                       const float* biasg, bool isTanh) {
        f32x4 acc[4];
        const int nt0 = wv * 4;
#pragma unroll
        for (int tt = 0; tt < 4; tt++) {
            float bvv = biasg[(nt0 + tt) * 16 + m16];
            f32x4 a0 = {bvv, bvv, bvv, bvv};
            acc[tt] = a0;
        }
#pragma unroll 2
        for (int kc = 0; kc < KC; kc++) {
            int ao = m16 * LDSW + kc * 32 + q * 8;
            bf16x8 ah = *(const bf16x8*)(iH + ao);
            bf16x8 al = *(const bf16x8*)(iL + ao);
#pragma unroll
            for (int tt = 0; tt < 4; tt++) {
                const unsigned short* bp = WF + (((nt0 + tt) * KC + kc) * 64 + lane) * 8;
                bf16x8 bh = *(const bf16x8*)bp;
                bf16x8 bl = *(const bf16x8*)(bp + planeE);
                acc[tt] = __builtin_amdgcn_mfma_f32_16x16x32_bf16(ah, bh, acc[tt], 0, 0, 0);
                acc[tt] = __builtin_amdgcn_mfma_f32_16x16x32_bf16(ah, bl, acc[tt], 0, 0, 0);
                acc[tt] = __builtin_amdgcn_mfma_f32_16x16x32_bf16(al, bh, acc[tt], 0, 0, 0);
            }
        }
#pragma unroll
        for (int tt = 0; tt < 4; tt++) {
            int n = (nt0 + tt) * 16 + m16;
#pragma unroll
            for (int r = 0; r < 4; r++) {
                int m = q * 4 + r;                  // C/D: col=lane&15, row=(lane>>4)*4+reg
                float v = acc[tt][r];
                v = isTanh ? tanhf(v) : fmaxf(v, 0.f);
                unsigned short hi = f2bf(v);
                oH[m * LDSW + n] = hi;
                oL[m * LDSW + n] = f2bf(v - bf2f(hi));
            }
        }
    };

    // stage 3: k = (H2 * A_r + c_r) * s ; fused Heun epilogue writes next y as bf16 hi/lo
    auto stage3 = [&](const unsigned short* iH, const unsigned short* iL,
                      unsigned short* oH, unsigned short* oL,
                      int ri, float s, bool modeB) {
        f32x4 acc[2];
        const int nt0 = wv * 2;
        const unsigned short* AF = A3F + ri * 65536;
#pragma unroll
        for (int tt = 0; tt < 2; tt++) {
            float cv = c_all[ri * 128 + (nt0 + tt) * 16 + m16];
            f32x4 a0 = {cv, cv, cv, cv};
            acc[tt] = a0;
        }
#pragma unroll 2
        for (int kc = 0; kc < 8; kc++) {
            int ao = m16 * LDSW + kc * 32 + q * 8;
            bf16x8 ah = *(const bf16x8*)(iH + ao);
            bf16x8 al = *(const bf16x8*)(iL + ao);
#pragma unroll
            for (int tt = 0; tt < 2; tt++) {
                const unsigned short* bp = AF + (((nt0 + tt) * 8 + kc) * 64 + lane) * 8;
                bf16x8 bh = *(const bf16x8*)bp;
                bf16x8 bl = *(const bf16x8*)(bp + 32768);
                acc[tt] = __builtin_amdgcn_mfma_f32_16x16x32_bf16(ah, bh, acc[tt], 0, 0, 0);
                acc[tt] = __builtin_amdgcn_mfma_f32_16x16x32_bf16(ah, bl, acc[tt], 0, 0, 0);
                acc[tt] = __builtin_amdgcn_mfma_f32_16x16x32_bf16(al, bh, acc[tt], 0, 0, 0);
            }
        }
#pragma unroll
        for (int tt = 0; tt < 2; tt++) {
            int n = (nt0 + tt) * 16 + m16;          // h index
#pragma unroll
            for (int r = 0; r < 4; r++) {
                int m = q * 4 + r;
                float kv = acc[tt][r] * s;
                float yn;
                if (!modeB) {                        // k1: stash k1, form y+dt*k1
                    K1[m * YST + n] = kv;
                    yn = Y[m * YST + n] + dt * kv;
                } else {                             // k2: y += 0.5*dt*(k1+k2)
                    yn = Y[m * YST + n] + 0.5f * dt * (K1[m * YST + n] + kv);
                    Y[m * YST + n] = yn;
                }
                unsigned short hi = f2bf(yn);
                oH[m * LDSW + n] = hi;
                oL[m * LDSW + n] = f2bf(yn - bf2f(hi));
            }
        }
    };

#pragma unroll 1
    for (int i = 0; i < 20; i++) {
        int r1 = r_arr[2 * i];     float s1 = s_arr[2 * i];
        int r2 = r_arr[2 * i + 1]; float s2 = s_arr[2 * i + 1];
        // ping-pong buffers: each phase reads one buffer, writes the other -> 1 barrier/phase
        stage12(PAhi, PAlo, PBhi, PBlo, W1F, 4, 32768, b1g, false); __syncthreads(); // h1 = relu
        stage12(PBhi, PBlo, PAhi, PAlo, W2F, 8, 65536, b2g, true);  __syncthreads(); // h2 = tanh
        stage3 (PAhi, PAlo, PBhi, PBlo, r1, s1, false);             __syncthreads(); // k1, y2bf
        stage12(PBhi, PBlo, PAhi, PAlo, W1F, 4, 32768, b1g, false); __syncthreads();
        stage12(PAhi, PAlo, PBhi, PBlo, W2F, 8, 65536, b2g, true);  __syncthreads();
        stage3 (PBhi, PBlo, PAhi, PAlo, r2, s2, true);              __syncthreads(); // y, ybf
    }

    // epilogue: logits + softmax
    if (t < 160) {
        int m = t / 10, c = t % 10;
        float acc = bout[c];
        for (int k = 0; k < 128; k++) acc += Y[m * YST + k] * Wout[c * 128 + k];
        lg[m][c] = acc;
    }
    __syncthreads();
    if (t < 16) {
        float mx = -1e30f;
#pragma unroll
        for (int c = 0; c < 10; c++) mx = fmaxf(mx, lg[t][c]);
        float ex[10], sum = 0.f;
#pragma unroll
        for (int c = 0; c < 10; c++) { ex[c] = expf(lg[t][c] - mx); sum += ex[c]; }
        float inv = __fdiv_rn(1.0f, sum);
#pragma unroll
        for (int c = 0; c < 10; c++) out[(row0 + t) * 10 + c] = ex[c] * inv;
    }
}

extern "C" void kernel_launch(void* const* d_in, const int* in_sizes, int n_in,
                              void* d_out, int out_size, void* d_ws, size_t ws_size,
                              hipStream_t stream) {
    const float* ts     = (const float*)d_in[0];
    const float* logsig = (const float*)d_in[1];
    const float* x0     = (const float*)d_in[2];
    const float* ivls   = (const float*)d_in[3];
    const float* Wvf1   = (const float*)d_in[4];
    const float* bvf1   = (const float*)d_in[5];
    const float* Wvf2   = (const float*)d_in[6];
    const float* bvf2   = (const float*)d_in[7];
    const float* Wm     = (const float*)d_in[8];
    const float* bm     = (const float*)d_in[9];
    const float* Win    = (const float*)d_in[10];
    const float* bin    = (const float*)d_in[11];
    const float* Wout   = (const float*)d_in[12];
    const float* bout   = (const float*)d_in[13];

    unsigned short* W1F = (unsigned short*)d_ws;        // 65536 ush (128KB)
    unsigned short* W2F = W1F + 65536;                  // 131072 ush (256KB)
    unsigned short* A3F = W2F + 131072;                 // 2097152 ush (4MB)
    float* c_all = (float*)(A3F + 2097152);             // 4096 f32 (16KB)
    float* out = (float*)d_out;

    pk_w<4><<<dim3(128), dim3(256), 0, stream>>>(Wvf1, W1F);
    pk_w<8><<<dim3(256), dim3(256), 0, stream>>>(Wvf2, W2F);
    pk_a3  <<<dim3(128), dim3(256), 0, stream>>>(Wm, logsig, A3F);
    pk_c   <<<dim3(16),  dim3(256), 0, stream>>>(bm, logsig, c_all);
    rde_main<<<dim3(32), dim3(256), 0, stream>>>(
        ts, x0, ivls, bvf1, bvf2, Win, bin, Wout, bout,
        W1F, W2F, A3F, c_all, out);
}

// Round 2
// 438.997 us; speedup vs baseline: 1.0180x; 1.0180x over previous
//
#include <hip/hip_runtime.h>

#define LDSW 264   // bf16 elems per LDS row (256 + 8 pad)
#define YST  132   // f32 elems per Y/K1 row (128 + 4 pad)

typedef __attribute__((ext_vector_type(8))) short bf16x8;
typedef __attribute__((ext_vector_type(4))) float f32x4;

__device__ __forceinline__ unsigned short f2bf(float f) {
    unsigned u = __float_as_uint(f);
    u += 0x7fffu + ((u >> 16) & 1u);          // RNE to bf16
    return (unsigned short)(u >> 16);
}
__device__ __forceinline__ float bf2f(unsigned short h) {
    return __uint_as_float(((unsigned)h) << 16);
}
// 5-op tanh: 1 - 2/(e^{2x}+1). Safe at +/-inf (no inf/inf). |err| ~1e-7.
__device__ __forceinline__ float fast_tanh(float x) {
    float e = __expf(2.0f * x);
    return 1.0f - 2.0f / (e + 1.0f);
}

// ---------------- fused precompute: all weights -> MFMA B-fragment layout, hi/lo bf16 ----
// F layout: [plane(2)][nt][kc][lane(64)][j(8)] ; value = W[n*K+k], n=nt*16+(l&15), k=kc*32+(l>>4)*8+j
__global__ __launch_bounds__(256) void pk_all(
    const float* __restrict__ Wvf1, const float* __restrict__ Wvf2,
    const float* __restrict__ Wm,   const float* __restrict__ bm,
    const float* __restrict__ logsig,
    unsigned short* __restrict__ W1F, unsigned short* __restrict__ W2F,
    unsigned short* __restrict__ A3F, float* __restrict__ c_all)
{
    __shared__ float ls[32][62];
    const int b = blockIdx.x, t = threadIdx.x;
    if (b < 128) {                      // W1: 128x128? no: (VF=256) x (H=128), KC=4
        int u = b * 256 + t;            // 32768 total
        int j = u & 7, l = (u >> 3) & 63;
        int kc = (u >> 9) & 3, nt = (u >> 9) >> 2;
        int n = nt * 16 + (l & 15), k = kc * 32 + (l >> 4) * 8 + j;
        float w = Wvf1[n * 128 + k];
        unsigned short hi = f2bf(w);
        W1F[u] = hi;
        W1F[32768 + u] = f2bf(w - bf2f(hi));
    } else if (b < 384) {               // W2: 256x256, KC=8
        int u = (b - 128) * 256 + t;    // 65536 total
        int j = u & 7, l = (u >> 3) & 63;
        int kc = (u >> 9) & 7, nt = (u >> 9) >> 3;
        int n = nt * 16 + (l & 15), k = kc * 32 + (l >> 4) * 8 + j;
        float w = Wvf2[n * 256 + k];
        unsigned short hi = f2bf(w);
        W2F[u] = hi;
        W2F[65536 + u] = f2bf(w - bf2f(hi));
    } else if (b < 512) {               // A_r[h,v] = sum_l Wm[(h*62+l)*256+v]*logsig[r,1+l]
        for (int e = t; e < 32 * 62; e += 256)
            ls[e / 62][e % 62] = logsig[(e / 62) * 63 + 1 + (e % 62)];
        __syncthreads();
        int u = (b - 384) * 256 + t;    // 32768 total
        int j = u & 7, l = (u >> 3) & 63, kc = (u >> 9) & 7, nt = (u >> 12) & 7;
        int h = nt * 16 + (l & 15);
        int v = kc * 32 + (l >> 4) * 8 + j;
        float acc[32];
#pragma unroll
        for (int r = 0; r < 32; r++) acc[r] = 0.f;
        for (int ll = 0; ll < 62; ll++) {
            float wv = Wm[(h * 62 + ll) * 256 + v];
#pragma unroll
            for (int r = 0; r < 32; r++) acc[r] += wv * ls[r][ll];
        }
        for (int r = 0; r < 32; r++) {
            unsigned short hi = f2bf(acc[r]);
            A3F[r * 65536 + u] = hi;
            A3F[r * 65536 + 32768 + u] = f2bf(acc[r] - bf2f(hi));
        }
    } else {                            // c_r[h] = bm[h,:] . seg_r
        int u = (b - 512) * 256 + t;    // 4096 = [r(32)][h(128)]
        int r = u >> 7, h = u & 127;
        float acc = 0.f;
        for (int ll = 0; ll < 62; ll++) acc += bm[h * 62 + ll] * logsig[r * 63 + 1 + ll];
        c_all[u] = acc;
    }
}

// ---------------- main fused kernel: 32 blocks x 16 rows, 8 waves, full 20-step Heun ---
// W2 B-fragments live in registers for the whole kernel (128 VGPR/wave);
// W1 / A_r fragments are preloaded to local arrays at phase start (one vmcnt drain).
// 3 independent accumulator chains per tile (ah*bh, ah*bl, al*bh) for MFMA ILP.
__global__ __launch_bounds__(512, 2) void rde_main(
    const float* __restrict__ ts, const float* __restrict__ x0,
    const float* __restrict__ intervals,
    const float* __restrict__ b1g, const float* __restrict__ b2g,
    const float* __restrict__ Win, const float* __restrict__ bin,
    const float* __restrict__ Wout, const float* __restrict__ bout,
    const unsigned short* __restrict__ W1F, const unsigned short* __restrict__ W2F,
    const unsigned short* __restrict__ A3F, const float* __restrict__ c_all,
    float* __restrict__ out)
{
    __shared__ unsigned short PAhi[16 * LDSW], PAlo[16 * LDSW];   // ping (hi/lo bf16)
    __shared__ unsigned short PBhi[16 * LDSW], PBlo[16 * LDSW];   // pong
    __shared__ float Y[16 * YST], K1[16 * YST];
    __shared__ float ivl[33];
    __shared__ int   r_arr[40];
    __shared__ float s_arr[40];
    __shared__ float lg[16][12];

    const int t    = threadIdx.x;
    const int lane = t & 63;
    const int wv   = t >> 6;        // wave 0..7
    const int m16  = lane & 15;
    const int q    = lane >> 4;
    const int row0 = blockIdx.x * 16;

    if (t < 33) ivl[t] = intervals[t];
    __syncthreads();

    const float ts0 = ts[0];
    const float dt  = __fdiv_rn(ts[32] - ts0, 20.0f);   // bit-exact vs reference

    if (t < 40) {   // searchsorted idx + 1/delta for all 40 VF evals
        int i = t >> 1;
        float tv = ts0 + (float)i * dt;
        if (t & 1) tv += dt;
        int p = 0;
        for (int j2 = 0; j2 < 32; j2++) p += (ivl[1 + j2] < tv) ? 1 : 0;
        int idx = p + 1;
        idx = idx < 1 ? 1 : idx;
        idx = idx > 32 ? 32 : idx;
        r_arr[t] = idx - 1;
        s_arr[t] = __fdiv_rn(1.0f, ivl[idx] - ivl[idx - 1]);
    }

    // persistent W2 fragments: wave wv owns n-tiles wv*2, wv*2+1 (128 VGPRs)
    bf16x8 w2h[2][8], w2l[2][8];
#pragma unroll
    for (int tt = 0; tt < 2; tt++)
#pragma unroll
        for (int kc = 0; kc < 8; kc++) {
            const unsigned short* bp = W2F + (((wv * 2 + tt) * 8 + kc) * 64 + lane) * 8;
            w2h[tt][kc] = *(const bf16x8*)bp;
            w2l[tt][kc] = *(const bf16x8*)(bp + 65536);
        }

    // y0 = x0 @ Win.T + bin
    for (int e = t; e < 2048; e += 512) {
        int m = e >> 7, h = e & 127;
        float acc = bin[h];
        const float* xr = x0 + (row0 + m) * 5;
#pragma unroll
        for (int d = 0; d < 5; d++) acc += xr[d] * Win[h * 5 + d];
        Y[m * YST + h] = acc;
    }
    __syncthreads();
    for (int e = t; e < 2048; e += 512) {   // initial bf16 hi/lo split -> ping
        int m = e >> 7, k = e & 127;
        float v = Y[m * YST + k];
        unsigned short hi = f2bf(v);
        PAhi[m * LDSW + k] = hi;
        PAlo[m * LDSW + k] = f2bf(v - bf2f(hi));
    }
    __syncthreads();

    // stage1: h1 = relu(y @ W1.T + b1), K=128 (KC=4), N=256; W1 frags streamed from L2
    auto stage1 = [&](const unsigned short* iH, const unsigned short* iL,
                      unsigned short* oH, unsigned short* oL) {
        bf16x8 bh[2][4], bl[2][4];
#pragma unroll
        for (int tt = 0; tt < 2; tt++)
#pragma unroll
            for (int kc = 0; kc < 4; kc++) {
                const unsigned short* bp = W1F + (((wv * 2 + tt) * 4 + kc) * 64 + lane) * 8;
                bh[tt][kc] = *(const bf16x8*)bp;
                bl[tt][kc] = *(const bf16x8*)(bp + 32768);
            }
        f32x4 aA[2], aB[2], aC[2];
#pragma unroll
        for (int tt = 0; tt < 2; tt++) {
            float bv = b1g[(wv * 2 + tt) * 16 + m16];
            aA[tt] = (f32x4){bv, bv, bv, bv};
            aB[tt] = (f32x4){0.f, 0.f, 0.f, 0.f};
            aC[tt] = (f32x4){0.f, 0.f, 0.f, 0.f};
        }
#pragma unroll
        for (int kc = 0; kc < 4; kc++) {
            int ao = m16 * LDSW + kc * 32 + q * 8;
            bf16x8 ah = *(const bf16x8*)(iH + ao);
            bf16x8 al = *(const bf16x8*)(iL + ao);
#pragma unroll
            for (int tt = 0; tt < 2; tt++) {
                aA[tt] = __builtin_amdgcn_mfma_f32_16x16x32_bf16(ah, bh[tt][kc], aA[tt], 0, 0, 0);
                aB[tt] = __builtin_amdgcn_mfma_f32_16x16x32_bf16(ah, bl[tt][kc], aB[tt], 0, 0, 0);
                aC[tt] = __builtin_amdgcn_mfma_f32_16x16x32_bf16(al, bh[tt][kc], aC[tt], 0, 0, 0);
            }
        }
#pragma unroll
        for (int tt = 0; tt < 2; tt++) {
            int n = (wv * 2 + tt) * 16 + m16;
#pragma unroll
            for (int r = 0; r < 4; r++) {
                int m = q * 4 + r;                  // C/D: col=lane&15, row=(lane>>4)*4+reg
                float v = fmaxf(aA[tt][r] + aB[tt][r] + aC[tt][r], 0.f);
                unsigned short hi = f2bf(v);
                oH[m * LDSW + n] = hi;
                oL[m * LDSW + n] = f2bf(v - bf2f(hi));
            }
        }
    };

    // stage2: h2 = tanh(h1 @ W2.T + b2), K=256 (KC=8), N=256; W2 frags in registers
    auto stage2 = [&](const unsigned short* iH, const unsigned short* iL,
                      unsigned short* oH, unsigned short* oL) {
        f32x4 aA[2], aB[2], aC[2];
#pragma unroll
        for (int tt = 0; tt < 2; tt++) {
            float bv = b2g[(wv * 2 + tt) * 16 + m16];
            aA[tt] = (f32x4){bv, bv, bv, bv};
            aB[tt] = (f32x4){0.f, 0.f, 0.f, 0.f};
            aC[tt] = (f32x4){0.f, 0.f, 0.f, 0.f};
        }
#pragma unroll
        for (int kc = 0; kc < 8; kc++) {
            int ao = m16 * LDSW + kc * 32 + q * 8;
            bf16x8 ah = *(const bf16x8*)(iH + ao);
            bf16x8 al = *(const bf16x8*)(iL + ao);
#pragma unroll
            for (int tt = 0; tt < 2; tt++) {
                aA[tt] = __builtin_amdgcn_mfma_f32_16x16x32_bf16(ah, w2h[tt][kc], aA[tt], 0, 0, 0);
                aB[tt] = __builtin_amdgcn_mfma_f32_16x16x32_bf16(ah, w2l[tt][kc], aB[tt], 0, 0, 0);
                aC[tt] = __builtin_amdgcn_mfma_f32_16x16x32_bf16(al, w2h[tt][kc], aC[tt], 0, 0, 0);
            }
        }
#pragma unroll
        for (int tt = 0; tt < 2; tt++) {
            int n = (wv * 2 + tt) * 16 + m16;
#pragma unroll
            for (int r = 0; r < 4; r++) {
                int m = q * 4 + r;
                float v = fast_tanh(aA[tt][r] + aB[tt][r] + aC[tt][r]);
                unsigned short hi = f2bf(v);
                oH[m * LDSW + n] = hi;
                oL[m * LDSW + n] = f2bf(v - bf2f(hi));
            }
        }
    };

    // stage3: k = (h2 @ A_r.T + c_r) * s, K=256, N=128; fused Heun epilogue
    auto stage3 = [&](const unsigned short* iH, const unsigned short* iL,
                      unsigned short* oH, unsigned short* oL,
                      int ri, float s, bool modeB) {
        const unsigned short* AF = A3F + ri * 65536;
        bf16x8 ph[8], pl[8];
#pragma unroll
        for (int kc = 0; kc < 8; kc++) {
            const unsigned short* bp = AF + ((wv * 8 + kc) * 64 + lane) * 8;
            ph[kc] = *(const bf16x8*)bp;
            pl[kc] = *(const bf16x8*)(bp + 32768);
        }
        float cv = c_all[ri * 128 + wv * 16 + m16];
        f32x4 aA = (f32x4){cv, cv, cv, cv};
        f32x4 aB = (f32x4){0.f, 0.f, 0.f, 0.f};
        f32x4 aC = (f32x4){0.f, 0.f, 0.f, 0.f};
#pragma unroll
        for (int kc = 0; kc < 8; kc++) {
            int ao = m16 * LDSW + kc * 32 + q * 8;
            bf16x8 ah = *(const bf16x8*)(iH + ao);
            bf16x8 al = *(const bf16x8*)(iL + ao);
            aA = __builtin_amdgcn_mfma_f32_16x16x32_bf16(ah, ph[kc], aA, 0, 0, 0);
            aB = __builtin_amdgcn_mfma_f32_16x16x32_bf16(ah, pl[kc], aB, 0, 0, 0);
            aC = __builtin_amdgcn_mfma_f32_16x16x32_bf16(al, ph[kc], aC, 0, 0, 0);
        }
        int n = wv * 16 + m16;                      // h index
#pragma unroll
        for (int r = 0; r < 4; r++) {
            int m = q * 4 + r;
            float kv = (aA[r] + aB[r] + aC[r]) * s;
            float yn;
            if (!modeB) {                            // k1: stash k1, form y+dt*k1
                K1[m * YST + n] = kv;
                yn = Y[m * YST + n] + dt * kv;
            } else {                                 // k2: y += 0.5*dt*(k1+k2)
                yn = Y[m * YST + n] + 0.5f * dt * (K1[m * YST + n] + kv);
                Y[m * YST + n] = yn;
            }
            unsigned short hi = f2bf(yn);
            oH[m * LDSW + n] = hi;
            oL[m * LDSW + n] = f2bf(yn - bf2f(hi));
        }
    };

#pragma unroll 1
    for (int i = 0; i < 20; i++) {
        int r1 = r_arr[2 * i];     float s1 = s_arr[2 * i];
        int r2 = r_arr[2 * i + 1]; float s2 = s_arr[2 * i + 1];
        stage1(PAhi, PAlo, PBhi, PBlo);                 __syncthreads(); // h1 = relu
        stage2(PBhi, PBlo, PAhi, PAlo);                 __syncthreads(); // h2 = tanh
        stage3(PAhi, PAlo, PBhi, PBlo, r1, s1, false);  __syncthreads(); // k1, y+dt*k1
        stage1(PBhi, PBlo, PAhi, PAlo);                 __syncthreads();
        stage2(PAhi, PAlo, PBhi, PBlo);                 __syncthreads();
        stage3(PBhi, PBlo, PAhi, PAlo, r2, s2, true);   __syncthreads(); // y update
    }

    // epilogue: logits + softmax
    if (t < 160) {
        int m = t / 10, c = t % 10;
        float acc = bout[c];
        for (int k = 0; k < 128; k++) acc += Y[m * YST + k] * Wout[c * 128 + k];
        lg[m][c] = acc;
    }
    __syncthreads();
    if (t < 16) {
        float mx = -1e30f;
#pragma unroll
        for (int c = 0; c < 10; c++) mx = fmaxf(mx, lg[t][c]);
        float ex[10], sum = 0.f;
#pragma unroll
        for (int c = 0; c < 10; c++) { ex[c] = expf(lg[t][c] - mx); sum += ex[c]; }
        float inv = __fdiv_rn(1.0f, sum);
#pragma unroll
        for (int c = 0; c < 10; c++) out[(row0 + t) * 10 + c] = ex[c] * inv;
    }
}

extern "C" void kernel_launch(void* const* d_in, const int* in_sizes, int n_in,
                              void* d_out, int out_size, void* d_ws, size_t ws_size,
                              hipStream_t stream) {
    const float* ts     = (const float*)d_in[0];
    const float* logsig = (const float*)d_in[1];
    const float* x0     = (const float*)d_in[2];
    const float* ivls   = (const float*)d_in[3];
    const float* Wvf1   = (const float*)d_in[4];
    const float* bvf1   = (const float*)d_in[5];
    const float* Wvf2   = (const float*)d_in[6];
    const float* bvf2   = (const float*)d_in[7];
    const float* Wm     = (const float*)d_in[8];
    const float* bm     = (const float*)d_in[9];
    const float* Win    = (const float*)d_in[10];
    const float* bin    = (const float*)d_in[11];
    const float* Wout   = (const float*)d_in[12];
    const float* bout   = (const float*)d_in[13];

    unsigned short* W1F = (unsigned short*)d_ws;        // 65536 ush (128KB)
    unsigned short* W2F = W1F + 65536;                  // 131072 ush (256KB)
    unsigned short* A3F = W2F + 131072;                 // 2097152 ush (4MB)
    float* c_all = (float*)(A3F + 2097152);             // 4096 f32 (16KB)
    float* out = (float*)d_out;

    pk_all<<<dim3(528), dim3(256), 0, stream>>>(Wvf1, Wvf2, Wm, bvf1 ? bm : bm, logsig,
                                                W1F, W2F, A3F, c_all);
    rde_main<<<dim3(32), dim3(512), 0, stream>>>(
        ts, x0, ivls, bvf1, bvf2, Win, bin, Wout, bout,
        W1F, W2F, A3F, c_all, out);
}

// Round 4
// 367.976 us; speedup vs baseline: 1.2145x; 1.1930x over previous
//
#include <hip/hip_runtime.h>

#define AW 264   // bf16 elems per activation LDS row (256 + 8 pad)

typedef __attribute__((ext_vector_type(8))) short bf16x8;
typedef __attribute__((ext_vector_type(4))) float f32x4;

__device__ __forceinline__ unsigned short f2bf(float f) {
    unsigned u = __float_as_uint(f);
    u += 0x7fffu + ((u >> 16) & 1u);          // RNE to bf16
    return (unsigned short)(u >> 16);
}
__device__ __forceinline__ float bf2f(unsigned short h) {
    return __uint_as_float(((unsigned)h) << 16);
}
// 5-op tanh: 1 - 2/(e^{2x}+1). Safe at +/-inf. |err| ~1e-7.
__device__ __forceinline__ float fast_tanh(float x) {
    float e = __expf(2.0f * x);
    return 1.0f - 2.0f / (e + 1.0f);
}
// Workgroup barrier that orders LDS only — does NOT drain vmcnt, so global
// prefetch loads stay in flight across it (unlike __syncthreads()).
__device__ __forceinline__ void bar_lds() {
    asm volatile("s_waitcnt lgkmcnt(0)\n\ts_barrier" ::: "memory");
}

// ---------------- fused precompute: weights -> MFMA B-frag layout, hi/lo bf16 ----
// F layout: [plane][nt][kc][lane(64)][j(8)]; value = W[n*K+k], n=nt*16+(l&15), k=kc*32+(l>>4)*8+j
__global__ __launch_bounds__(256) void pk_all(
    const float* __restrict__ Wvf1, const float* __restrict__ Wvf2,
    const float* __restrict__ Wm,   const float* __restrict__ bm,
    const float* __restrict__ logsig,
    unsigned short* __restrict__ W1F, unsigned short* __restrict__ W2F,
    unsigned short* __restrict__ A3F, float* __restrict__ c_all)
{
    __shared__ float ls[32][62];
    const int b = blockIdx.x, t = threadIdx.x;
    if (b < 128) {                      // W1: N=256 x K=128, KC=4
        int u = b * 256 + t;            // 32768 total
        int j = u & 7, l = (u >> 3) & 63;
        int kc = (u >> 9) & 3, nt = (u >> 9) >> 2;
        int n = nt * 16 + (l & 15), k = kc * 32 + (l >> 4) * 8 + j;
        float w = Wvf1[n * 128 + k];
        unsigned short hi = f2bf(w);
        W1F[u] = hi;
        W1F[32768 + u] = f2bf(w - bf2f(hi));
    } else if (b < 384) {               // W2: 256x256, KC=8
        int u = (b - 128) * 256 + t;    // 65536 total
        int j = u & 7, l = (u >> 3) & 63;
        int kc = (u >> 9) & 7, nt = (u >> 9) >> 3;
        int n = nt * 16 + (l & 15), k = kc * 32 + (l >> 4) * 8 + j;
        float w = Wvf2[n * 256 + k];
        unsigned short hi = f2bf(w);
        W2F[u] = hi;
        W2F[65536 + u] = f2bf(w - bf2f(hi));
    } else if (b < 512) {               // A_r[h,v] = sum_l Wm[(h*62+l)*256+v]*logsig[r,1+l]
        for (int e = t; e < 32 * 62; e += 256)
            ls[e / 62][e % 62] = logsig[(e / 62) * 63 + 1 + (e % 62)];
        __syncthreads();
        int u = (b - 384) * 256 + t;    // 32768 per r
        int j = u & 7, l = (u >> 3) & 63, kc = (u >> 9) & 7, nt = (u >> 12) & 7;
        int h = nt * 16 + (l & 15);
        int v = kc * 32 + (l >> 4) * 8 + j;
        float acc[32];
#pragma unroll
        for (int r = 0; r < 32; r++) acc[r] = 0.f;
        for (int ll = 0; ll < 62; ll++) {
            float wv = Wm[(h * 62 + ll) * 256 + v];
#pragma unroll
            for (int r = 0; r < 32; r++) acc[r] += wv * ls[r][ll];
        }
        for (int r = 0; r < 32; r++) {
            unsigned short hi = f2bf(acc[r]);
            A3F[r * 65536 + u] = hi;
            A3F[r * 65536 + 32768 + u] = f2bf(acc[r] - bf2f(hi));
        }
    } else {                            // c_r[h] = bm[h,:] . seg_r
        int u = (b - 512) * 256 + t;    // 4096 = [r(32)][h(128)]
        int r = u >> 7, h = u & 127;
        float acc = 0.f;
        for (int ll = 0; ll < 62; ll++) acc += bm[h * 62 + ll] * logsig[r * 63 + 1 + ll];
        c_all[u] = acc;
    }
}

// ---------------- main fused kernel: 32 blocks x 16 rows, 8 waves, 20-step Heun ---
// bf16 hi/lo 3-chain numerics (round-1 verified). W1 hi/lo resident in LDS (128KB),
// W2 hi/lo resident in registers (128 VGPR/wave), A_r hi/lo prefetched to regs at
// eval start (vmcnt NOT drained by bar_lds). Y/K1 state in registers. In-place
// activation buffer with read-barrier-write.
__global__ __launch_bounds__(512, 2) void rde_main(
    const float* __restrict__ ts, const float* __restrict__ x0,
    const float* __restrict__ intervals,
    const float* __restrict__ b1g, const float* __restrict__ b2g,
    const float* __restrict__ Win, const float* __restrict__ bin,
    const float* __restrict__ Wout, const float* __restrict__ bout,
    const unsigned short* __restrict__ W1F, const unsigned short* __restrict__ W2F,
    const unsigned short* __restrict__ A3F, const float* __restrict__ c_all,
    float* __restrict__ out)
{
    __shared__ __align__(16) unsigned short W1s[65536];           // 128 KB hi+lo
    __shared__ __align__(16) unsigned short AH[16 * AW];          // act hi (in-place)
    __shared__ __align__(16) unsigned short AL[16 * AW];          // act lo
    __shared__ float ivl[33];
    __shared__ int   r_arr[40];
    __shared__ float s_arr[40];
    __shared__ float lg[16][12];

    const int t    = threadIdx.x;
    const int lane = t & 63;
    const int wv   = t >> 6;        // wave 0..7
    const int m16  = lane & 15;
    const int q    = lane >> 4;
    const int row0 = blockIdx.x * 16;

    if (t < 33) ivl[t] = intervals[t];
    // W1 hi+lo -> LDS (once): 65536 halfs = 8192 uint4
    for (int e = t; e < 8192; e += 512)
        ((uint4*)W1s)[e] = ((const uint4*)W1F)[e];
    __syncthreads();

    const float ts0 = ts[0];
    const float dt  = __fdiv_rn(ts[32] - ts0, 20.0f);   // bit-exact vs reference

    if (t < 40) {   // searchsorted idx + 1/delta for all 40 VF evals
        int i = t >> 1;
        float tv = ts0 + (float)i * dt;
        if (t & 1) tv += dt;
        int p = 0;
        for (int j2 = 0; j2 < 32; j2++) p += (ivl[1 + j2] < tv) ? 1 : 0;
        int idx = p + 1;
        idx = idx < 1 ? 1 : idx;
        idx = idx > 32 ? 32 : idx;
        r_arr[t] = idx - 1;
        s_arr[t] = __fdiv_rn(1.0f, ivl[idx] - ivl[idx - 1]);
    }

    // persistent W2 hi/lo fragments: wave wv owns n-tiles wv*2, wv*2+1 (128 VGPRs)
    bf16x8 w2h[2][8], w2l[2][8];
#pragma unroll
    for (int tt = 0; tt < 2; tt++)
#pragma unroll
        for (int kc = 0; kc < 8; kc++) {
            const unsigned short* bp = W2F + (((wv * 2 + tt) * 8 + kc) * 64 + lane) * 8;
            w2h[tt][kc] = *(const bf16x8*)bp;
            w2l[tt][kc] = *(const bf16x8*)(bp + 65536);
        }

    // y0 = x0 @ Win.T + bin  -> Y regs (C/D mapping: row q*4+r, col wv*16+m16) + ACT
    float Y[4], K1[4];
#pragma unroll
    for (int r = 0; r < 4; r++) {
        int m = q * 4 + r, h = wv * 16 + m16;
        float acc = bin[h];
        const float* xr = x0 + (row0 + m) * 5;
#pragma unroll
        for (int d = 0; d < 5; d++) acc += xr[d] * Win[h * 5 + d];
        Y[r] = acc;
        K1[r] = 0.f;
        unsigned short hi = f2bf(acc);
        AH[m * AW + h] = hi;
        AL[m * AW + h] = f2bf(acc - bf2f(hi));
    }
    __syncthreads();

#pragma unroll 1
    for (int i = 0; i < 20; i++) {
#pragma unroll
        for (int half = 0; half < 2; half++) {
            const int e  = 2 * i + half;
            const int ri = r_arr[e];
            const float s = s_arr[e];

            // ---- A_r hi/lo prefetch (consumed in stage3; in flight across bar_lds) ----
            bf16x8 pah[8], pal[8];
#pragma unroll
            for (int kc = 0; kc < 8; kc++) {
                const unsigned short* bp = A3F + ri * 65536 + ((wv * 8 + kc) * 64 + lane) * 8;
                pah[kc] = *(const bf16x8*)bp;
                pal[kc] = *(const bf16x8*)(bp + 32768);
            }
            const float cv = c_all[ri * 128 + wv * 16 + m16];

            // ---- stage1 compute: h1 = relu(y @ W1.T + b1), K=128, W1 from LDS ----
            f32x4 aA[2], aB[2], aC[2];
#pragma unroll
            for (int tt = 0; tt < 2; tt++) {
                float bv = b1g[(wv * 2 + tt) * 16 + m16];
                aA[tt] = (f32x4){bv, bv, bv, bv};
                aB[tt] = (f32x4){0.f, 0.f, 0.f, 0.f};
                aC[tt] = (f32x4){0.f, 0.f, 0.f, 0.f};
            }
#pragma unroll
            for (int kc = 0; kc < 4; kc++) {
                int ao = m16 * AW + kc * 32 + q * 8;
                bf16x8 ah = *(const bf16x8*)(AH + ao);
                bf16x8 al = *(const bf16x8*)(AL + ao);
#pragma unroll
                for (int tt = 0; tt < 2; tt++) {
                    int wb = (((wv * 2 + tt) * 4 + kc) * 64 + lane) * 8;
                    bf16x8 bh = *(const bf16x8*)(W1s + wb);
                    bf16x8 bl = *(const bf16x8*)(W1s + 32768 + wb);
                    aA[tt] = __builtin_amdgcn_mfma_f32_16x16x32_bf16(ah, bh, aA[tt], 0, 0, 0);
                    aB[tt] = __builtin_amdgcn_mfma_f32_16x16x32_bf16(ah, bl, aB[tt], 0, 0, 0);
                    aC[tt] = __builtin_amdgcn_mfma_f32_16x16x32_bf16(al, bh, aC[tt], 0, 0, 0);
                }
            }
            bar_lds();          // all reads of y done
#pragma unroll
            for (int tt = 0; tt < 2; tt++) {        // commit h1 (hi/lo)
                int n = (wv * 2 + tt) * 16 + m16;
#pragma unroll
                for (int r = 0; r < 4; r++) {
                    int m = q * 4 + r;              // C/D: col=lane&15, row=(lane>>4)*4+reg
                    float v = fmaxf(aA[tt][r] + aB[tt][r] + aC[tt][r], 0.f);
                    unsigned short hi = f2bf(v);
                    AH[m * AW + n] = hi;
                    AL[m * AW + n] = f2bf(v - bf2f(hi));
                }
            }
            bar_lds();

            // ---- stage2 compute: h2 = tanh(h1 @ W2.T + b2), K=256, W2 in regs ----
#pragma unroll
            for (int tt = 0; tt < 2; tt++) {
                float bv = b2g[(wv * 2 + tt) * 16 + m16];
                aA[tt] = (f32x4){bv, bv, bv, bv};
                aB[tt] = (f32x4){0.f, 0.f, 0.f, 0.f};
                aC[tt] = (f32x4){0.f, 0.f, 0.f, 0.f};
            }
#pragma unroll
            for (int kc = 0; kc < 8; kc++) {
                int ao = m16 * AW + kc * 32 + q * 8;
                bf16x8 ah = *(const bf16x8*)(AH + ao);
                bf16x8 al = *(const bf16x8*)(AL + ao);
#pragma unroll
                for (int tt = 0; tt < 2; tt++) {
                    aA[tt] = __builtin_amdgcn_mfma_f32_16x16x32_bf16(ah, w2h[tt][kc], aA[tt], 0, 0, 0);
                    aB[tt] = __builtin_amdgcn_mfma_f32_16x16x32_bf16(ah, w2l[tt][kc], aB[tt], 0, 0, 0);
                    aC[tt] = __builtin_amdgcn_mfma_f32_16x16x32_bf16(al, w2h[tt][kc], aC[tt], 0, 0, 0);
                }
            }
            bar_lds();
#pragma unroll
            for (int tt = 0; tt < 2; tt++) {        // commit h2 (hi/lo)
                int n = (wv * 2 + tt) * 16 + m16;
#pragma unroll
                for (int r = 0; r < 4; r++) {
                    int m = q * 4 + r;
                    float v = fast_tanh(aA[tt][r] + aB[tt][r] + aC[tt][r]);
                    unsigned short hi = f2bf(v);
                    AH[m * AW + n] = hi;
                    AL[m * AW + n] = f2bf(v - bf2f(hi));
                }
            }
            bar_lds();

            // ---- stage3: k = (h2 @ A_r.T + c_r) * s, N=128 (1 n-tile/wave) ----
            f32x4 kA = (f32x4){cv, cv, cv, cv};
            f32x4 kB = (f32x4){0.f, 0.f, 0.f, 0.f};
            f32x4 kC = (f32x4){0.f, 0.f, 0.f, 0.f};
#pragma unroll
            for (int kc = 0; kc < 8; kc++) {
                int ao = m16 * AW + kc * 32 + q * 8;
                bf16x8 ah = *(const bf16x8*)(AH + ao);
                bf16x8 al = *(const bf16x8*)(AL + ao);
                kA = __builtin_amdgcn_mfma_f32_16x16x32_bf16(ah, pah[kc], kA, 0, 0, 0);
                kB = __builtin_amdgcn_mfma_f32_16x16x32_bf16(ah, pal[kc], kB, 0, 0, 0);
                kC = __builtin_amdgcn_mfma_f32_16x16x32_bf16(al, pah[kc], kC, 0, 0, 0);
            }
            bar_lds();
            {                                       // commit: Heun update in regs + y->ACT
                int n = wv * 16 + m16;              // h index
#pragma unroll
                for (int r = 0; r < 4; r++) {
                    int m = q * 4 + r;
                    float kv = (kA[r] + kB[r] + kC[r]) * s;
                    float yn;
                    if (half == 0) {                 // k1: stash, form y+dt*k1
                        K1[r] = kv;
                        yn = Y[r] + dt * kv;
                    } else {                         // k2: y += 0.5*dt*(k1+k2)
                        yn = Y[r] + 0.5f * dt * (K1[r] + kv);
                        Y[r] = yn;
                    }
                    unsigned short hi = f2bf(yn);
                    AH[m * AW + n] = hi;
                    AL[m * AW + n] = f2bf(yn - bf2f(hi));
                }
            }
            bar_lds();
        }
    }

    // epilogue: Y regs -> LDS floats (reuse AH region: 16 rows x 132 f32 = 8448 B)
    float* Ys = (float*)AH;
#pragma unroll
    for (int r = 0; r < 4; r++)
        Ys[(q * 4 + r) * 132 + wv * 16 + m16] = Y[r];
    __syncthreads();
    if (t < 160) {                  // logits
        int m = t / 10, c = t % 10;
        float acc = bout[c];
        for (int k = 0; k < 128; k++) acc += Ys[m * 132 + k] * Wout[c * 128 + k];
        lg[m][c] = acc;
    }
    __syncthreads();
    if (t < 16) {                   // softmax
        float mx = -1e30f;
#pragma unroll
        for (int c = 0; c < 10; c++) mx = fmaxf(mx, lg[t][c]);
        float ex[10], sum = 0.f;
#pragma unroll
        for (int c = 0; c < 10; c++) { ex[c] = expf(lg[t][c] - mx); sum += ex[c]; }
        float inv = __fdiv_rn(1.0f, sum);
#pragma unroll
        for (int c = 0; c < 10; c++) out[(row0 + t) * 10 + c] = ex[c] * inv;
    }
}

extern "C" void kernel_launch(void* const* d_in, const int* in_sizes, int n_in,
                              void* d_out, int out_size, void* d_ws, size_t ws_size,
                              hipStream_t stream) {
    const float* ts     = (const float*)d_in[0];
    const float* logsig = (const float*)d_in[1];
    const float* x0     = (const float*)d_in[2];
    const float* ivls   = (const float*)d_in[3];
    const float* Wvf1   = (const float*)d_in[4];
    const float* bvf1   = (const float*)d_in[5];
    const float* Wvf2   = (const float*)d_in[6];
    const float* bvf2   = (const float*)d_in[7];
    const float* Wm     = (const float*)d_in[8];
    const float* bm     = (const float*)d_in[9];
    const float* Win    = (const float*)d_in[10];
    const float* bin    = (const float*)d_in[11];
    const float* Wout   = (const float*)d_in[12];
    const float* bout   = (const float*)d_in[13];

    unsigned short* W1F = (unsigned short*)d_ws;        // 65536 ush (128KB, hi+lo)
    unsigned short* W2F = W1F + 65536;                  // 131072 ush (256KB, hi+lo)
    unsigned short* A3F = W2F + 131072;                 // 2097152 ush (4MB, 32 r's hi+lo)
    float* c_all = (float*)(A3F + 2097152);             // 4096 f32 (16KB)
    float* out = (float*)d_out;

    pk_all<<<dim3(528), dim3(256), 0, stream>>>(Wvf1, Wvf2, Wm, bm, logsig,
                                                W1F, W2F, A3F, c_all);
    rde_main<<<dim3(32), dim3(512), 0, stream>>>(
        ts, x0, ivls, bvf1, bvf2, Win, bin, Wout, bout,
        W1F, W2F, A3F, c_all, out);
}